// Round 1
// 232.103 us; speedup vs baseline: 1.0037x; 1.0037x over previous
//
#include <hip/hip_runtime.h>
#include <math.h>

#define NB 32
#define CC 1024
#define SS 784
#define SP 832           // padded S (52*16); sa pad region is zeroed
#define DD 128
#define KK 64
#define OUTD 1024
#define KD 8192          // K*D
#define NSPLIT 13        // vlad s-splits (64 s each)
#define PSPLIT 32        // split-K for projection (8192 = 32*256)

// workspace layout (BYTE offsets)  -- total ~29.5 MB (< 30.9 MB known-good)
#define OFF_XN    0                                   // bf16 (N,D,SP)
#define OFF_SA    (OFF_XN + NB*DD*SP*2)               // bf16 (N,K,SP)
#define OFF_WPK   (OFF_SA + NB*KK*SP*2)               // bf16 Wpool frag-packed (32*8*64*8)
#define OFF_WCK   (OFF_WPK + 32*8*64*8*2)             // bf16 Wconv frag-packed (16*64*8)
#define OFF_VLADP (OFF_WCK + 16*64*8*2)               // f32 (N,NSPLIT,KD) packed C-layout
#define OFF_SASUM (OFF_VLADP + NB*NSPLIT*KD*4)        // f32 (N,NSPLIT,K)
#define OFF_VLADN (OFF_SASUM + NB*NSPLIT*KK*4)        // f32 (N,KD)
#define OFF_OUTP  (OFF_VLADN + NB*KD*4)               // f32 (PSPLIT,N,OUT)

typedef __attribute__((ext_vector_type(8))) short bf16x8;   // 8 bf16 = 4 VGPRs
typedef __attribute__((ext_vector_type(4))) float f32x4;
typedef __attribute__((ext_vector_type(4))) unsigned int u32x4;

__device__ __forceinline__ unsigned int pk_bf16(float a, float b) {
    unsigned int ua = __builtin_bit_cast(unsigned int, a);
    unsigned int ub = __builtin_bit_cast(unsigned int, b);
    ua += 0x7FFFu + ((ua >> 16) & 1u);
    ub += 0x7FFFu + ((ub >> 16) & 1u);
    return (ua >> 16) | (ub & 0xFFFF0000u);
}
__device__ __forceinline__ unsigned short f2bf(float a) {
    unsigned int ua = __builtin_bit_cast(unsigned int, a);
    ua += 0x7FFFu + ((ua >> 16) & 1u);
    return (unsigned short)(ua >> 16);
}
__device__ __forceinline__ float bf2f(unsigned short u) {
    unsigned int v = ((unsigned int)u) << 16;
    return __builtin_bit_cast(float, v);
}

// ---------------------------------------------------------------------------
// K1: pack Wpool (128x1024) and Wconv (64x128) into MFMA A-fragment-ordered
// bf16 arrays.  Wpk: [kt(32)][mt(8)][lane(64)][8]; Wck: [tile(16)][lane(64)][8]
// ---------------------------------------------------------------------------
__global__ __launch_bounds__(256)
void pack_weights(const float* __restrict__ Wpool, const float* __restrict__ Wconv,
                  unsigned short* __restrict__ Wpk, unsigned short* __restrict__ Wck)
{
    const int b = blockIdx.x;
    const int t = threadIdx.x;
    if (b < 8) {
#pragma unroll
        for (int i = 0; i < 8; i++) {
            const int id = t + 256 * i;            // 0..2047
            const int ktl = id >> 9;               // 0..3
            const int mt  = (id >> 6) & 7;
            const int l   = id & 63;
            const int lm = l & 15, quad = l >> 4;
            const int kt = b * 4 + ktl;
            const int d = mt * 16 + lm;
            const int c = kt * 32 + quad * 8;
            const float4 v0 = *(const float4*)&Wpool[(size_t)d * CC + c];
            const float4 v1 = *(const float4*)&Wpool[(size_t)d * CC + c + 4];
            unsigned int* dst = (unsigned int*)&Wpk[(size_t)((kt * 8 + mt) * 64 + l) * 8];
            dst[0] = pk_bf16(v0.x, v0.y); dst[1] = pk_bf16(v0.z, v0.w);
            dst[2] = pk_bf16(v1.x, v1.y); dst[3] = pk_bf16(v1.z, v1.w);
        }
    } else {
#pragma unroll
        for (int i = 0; i < 4; i++) {
            const int id = t + 256 * i;            // 0..1023
            const int tile = id >> 6;
            const int l = id & 63;
            const int lm = l & 15, quad = l >> 4;
            const int k = (tile >> 2) * 16 + lm;
            const int d = (tile & 3) * 32 + quad * 8;
            const float4 v0 = *(const float4*)&Wconv[(size_t)k * DD + d];
            const float4 v1 = *(const float4*)&Wconv[(size_t)k * DD + d + 4];
            unsigned int* dst = (unsigned int*)&Wck[(size_t)(tile * 64 + l) * 8];
            dst[0] = pk_bf16(v0.x, v0.y); dst[1] = pk_bf16(v0.z, v0.w);
            dst[2] = pk_bf16(v1.x, v1.y); dst[3] = pk_bf16(v1.z, v1.w);
        }
    }
}

// ---------------------------------------------------------------------------
// K2: pool GEMM + bias + L2-norm + assign GEMM + softmax.
// Block tile 128d x 16s, grid (52, N) = 1664 blocks.
// v2 changes vs previous session's kernel:
//  - staging loads vectorized: 16x dwordx4 per thread (was 64x dword),
//    in-register transpose folded into the bf16 pack; LDS write pattern
//    XOR-swizzled (s ^= oct&7) to kill the resulting 16-way bank conflict,
//    same swizzle applied on the phase-2 ds_read (stays conflict-free).
//  - staging split into 2 halves of 512 c: LDS 37.4 KB -> 20.5 KB ->
//    6 blocks/CU (24 waves/CU, near single-round dispatch vs 1.6 rounds).
//    Half-1 global loads issued BEFORE compute-half-0 (async-stage split):
//    HBM latency hides under the first 16 MFMA K-steps.
//  - pure-pad s-blocks (s0 >= 784; 96 of 1664 blocks) zero xn/sa and exit.
// Numerics of real outputs are bit-identical to the previous version.
// ---------------------------------------------------------------------------
__global__ __launch_bounds__(256, 6)
void pool_norm_assign(const float* __restrict__ x, const unsigned short* __restrict__ Wpk,
                      const float* __restrict__ bpool, const unsigned short* __restrict__ Wck,
                      const float* __restrict__ bconv,
                      unsigned short* __restrict__ xn, unsigned short* __restrict__ sa)
{
    const int n  = blockIdx.y;
    const int s0 = blockIdx.x * 16;
    const int t  = threadIdx.x;
    const int l  = t & 63;
    const int w  = t >> 6;       // wave 0..3 -> mt pair {2w, 2w+1}
    const int lm = l & 15;
    const int quad = l >> 4;

    __shared__ alignas(16) unsigned short Bst[64 * 16 * 8];   // 16 KB (one 512-c half)
    __shared__ alignas(16) unsigned short xnT[16 * 16 * 8];   // 4 KB [dblk][s][8]
    __shared__ float red[4][16];
    __shared__ float sums[4][16];

    unsigned short* xnp = xn + (size_t)n * DD * SP;
    unsigned short* sap = sa + (size_t)n * KK * SP;

    if (s0 >= SS) {
        // pure-pad block: zero xn and sa for this s-slice, exit.
        const u32x4 z = (u32x4){0u, 0u, 0u, 0u};
        const int d  = t >> 1;
        const int hh = t & 1;
        *(u32x4*)&xnp[(size_t)d * SP + s0 + hh * 8] = z;
        if (t < 128) {
            const int k = t >> 1;
            *(u32x4*)&sap[(size_t)k * SP + s0 + hh * 8] = z;
        }
        return;
    }

    // ---- PHASE 1a: stage half 0 (c in [0,512)) with vectorized loads.
    // thread: oct = t>>2 (8 consecutive c), squad = t&3 (4 consecutive s).
    const int oct   = t >> 2;
    const int squad = t & 3;
    const int s_l4  = squad * 4;
    const float* xbase = x + (size_t)n * CC * SS + s0 + s_l4;   // all in-bounds: SS = 49*16

    {
        f32x4 f[8];
#pragma unroll
        for (int j = 0; j < 8; j++)
            f[j] = *(const f32x4*)&xbase[(size_t)(oct * 8 + j) * SS];
#pragma unroll
        for (int ss = 0; ss < 4; ss++) {
            const int s = s_l4 + ss;
            unsigned int* dst = (unsigned int*)&Bst[(size_t)(oct * 16 + (s ^ (oct & 7))) * 8];
            dst[0] = pk_bf16(f[0][ss], f[1][ss]); dst[1] = pk_bf16(f[2][ss], f[3][ss]);
            dst[2] = pk_bf16(f[4][ss], f[5][ss]); dst[3] = pk_bf16(f[6][ss], f[7][ss]);
        }
    }
    __syncthreads();

    // ---- issue half-1 loads now (complete during compute half 0)
    f32x4 g[8];
#pragma unroll
    for (int j = 0; j < 8; j++)
        g[j] = *(const f32x4*)&xbase[(size_t)(512 + oct * 8 + j) * SS];

    // ---- PHASE 2: pool GEMM K-loop, split in two 16-step halves.
    f32x4 acc[2];
    acc[0] = (f32x4){0.f, 0.f, 0.f, 0.f};
    acc[1] = (f32x4){0.f, 0.f, 0.f, 0.f};

    bf16x8 a_nxt[2];
#pragma unroll
    for (int i = 0; i < 2; i++)
        a_nxt[i] = *(const bf16x8*)&Wpk[(size_t)((0 * 8 + w * 2 + i) * 64 + l) * 8];

    for (int kt = 0; kt < 16; kt++) {
        const bf16x8 a0 = a_nxt[0], a1 = a_nxt[1];
#pragma unroll
        for (int i = 0; i < 2; i++)
            a_nxt[i] = *(const bf16x8*)&Wpk[(size_t)(((kt + 1) * 8 + w * 2 + i) * 64 + l) * 8];
        const int cb = kt * 4 + quad;
        const bf16x8 bfrag = *(const bf16x8*)&Bst[(size_t)(cb * 16 + (lm ^ (cb & 7))) * 8];
        acc[0] = __builtin_amdgcn_mfma_f32_16x16x32_bf16(a0, bfrag, acc[0], 0, 0, 0);
        acc[1] = __builtin_amdgcn_mfma_f32_16x16x32_bf16(a1, bfrag, acc[1], 0, 0, 0);
    }
    __syncthreads();   // Bst half-0 reads done (also drains g)

    // ---- PHASE 1b: pack + write half 1
#pragma unroll
    for (int ss = 0; ss < 4; ss++) {
        const int s = s_l4 + ss;
        unsigned int* dst = (unsigned int*)&Bst[(size_t)(oct * 16 + (s ^ (oct & 7))) * 8];
        dst[0] = pk_bf16(g[0][ss], g[1][ss]); dst[1] = pk_bf16(g[2][ss], g[3][ss]);
        dst[2] = pk_bf16(g[4][ss], g[5][ss]); dst[3] = pk_bf16(g[6][ss], g[7][ss]);
    }
    __syncthreads();

    for (int kt = 16; kt < 32; kt++) {
        const bf16x8 a0 = a_nxt[0], a1 = a_nxt[1];
        if (kt < 31) {
#pragma unroll
            for (int i = 0; i < 2; i++)
                a_nxt[i] = *(const bf16x8*)&Wpk[(size_t)(((kt + 1) * 8 + w * 2 + i) * 64 + l) * 8];
        }
        const int cb = (kt & 15) * 4 + quad;
        const bf16x8 bfrag = *(const bf16x8*)&Bst[(size_t)(cb * 16 + (lm ^ (cb & 7))) * 8];
        acc[0] = __builtin_amdgcn_mfma_f32_16x16x32_bf16(a0, bfrag, acc[0], 0, 0, 0);
        acc[1] = __builtin_amdgcn_mfma_f32_16x16x32_bf16(a1, bfrag, acc[1], 0, 0, 0);
    }

    // ---- PHASE 3a: bias + L2-norm over d.  C layout: d=(2w+i)*16+quad*4+r, s=lm
    float vals[2][4];
    float ssq = 0.f;
#pragma unroll
    for (int i = 0; i < 2; i++)
#pragma unroll
        for (int r = 0; r < 4; r++) {
            const int d = (w * 2 + i) * 16 + quad * 4 + r;
            const float v = acc[i][r] + bpool[d];
            vals[i][r] = v; ssq += v * v;
        }
    ssq += __shfl_xor(ssq, 16, 64);
    ssq += __shfl_xor(ssq, 32, 64);
    if (quad == 0) red[w][lm] = ssq;
    __syncthreads();
    const float scale = 1.f / fmaxf(sqrtf(red[0][lm] + red[1][lm] + red[2][lm] + red[3][lm]), 1e-12f);
    const int sg = s0 + lm;
#pragma unroll
    for (int i = 0; i < 2; i++)
#pragma unroll
        for (int r = 0; r < 4; r++) {
            const int d = (w * 2 + i) * 16 + quad * 4 + r;
            const float v = vals[i][r] * scale;
            xnp[(size_t)d * SP + sg] = f2bf(v);
            xnT[(size_t)(((d >> 3) * 16) + lm) * 8 + (d & 7)] = f2bf(v);
        }
    __syncthreads();

    // ---- PHASE 3b: assign GEMM (64k x 16s), wave w -> k-tile w
    f32x4 acc2 = (f32x4){0.f, 0.f, 0.f, 0.f};
#pragma unroll
    for (int dsv = 0; dsv < 4; dsv++) {
        const bf16x8 bfrag = *(const bf16x8*)&xnT[(size_t)((dsv * 4 + quad) * 16 + lm) * 8];
        const bf16x8 afrag = *(const bf16x8*)&Wck[(size_t)((w * 4 + dsv) * 64 + l) * 8];
        acc2 = __builtin_amdgcn_mfma_f32_16x16x32_bf16(afrag, bfrag, acc2, 0, 0, 0);
    }
    // softmax over k (|logits| <= ~1.5 since x-hat unit-norm: no max-sub needed)
    float e[4]; float ps = 0.f;
#pragma unroll
    for (int r = 0; r < 4; r++) {
        const int k = w * 16 + quad * 4 + r;
        e[r] = expf(acc2[r] + bconv[k]);
        ps += e[r];
    }
    ps += __shfl_xor(ps, 16, 64);
    ps += __shfl_xor(ps, 32, 64);
    if (quad == 0) sums[w][lm] = ps;
    __syncthreads();
    const float inv = 1.f / (sums[0][lm] + sums[1][lm] + sums[2][lm] + sums[3][lm]);
#pragma unroll
    for (int r = 0; r < 4; r++) {
        const int k = w * 16 + quad * 4 + r;
        sap[(size_t)k * SP + sg] = f2bf(e[r] * inv);
    }
}

// ---------------------------------------------------------------------------
// K3: vlad GEMM (MFMA, fragment loads direct from global, no LDS, no barrier):
// C stored PACKED: vp[(kq*DD+d)*4 + r], k = kq*4+r -> 16B f32x4 stores.
// grid (NSPLIT, N) = 416 blocks; wave tile 32k x 64d.
// ---------------------------------------------------------------------------
__global__ __launch_bounds__(256)
void vlad_mfma(const unsigned short* __restrict__ xn, const unsigned short* __restrict__ sa,
               float* __restrict__ vladp, float* __restrict__ sasump)
{
    const int p = blockIdx.x;
    const int n = blockIdx.y;
    const int t = threadIdx.x;
    const int l = t & 63;
    const int w = t >> 6;
    const int kth = w & 1, nh = w >> 1;
    const int lm = l & 15, quad = l >> 4;

    const unsigned short* sap = sa + (size_t)n * KK * SP;
    const unsigned short* xnp = xn + (size_t)n * DD * SP;

    f32x4 acc[2][4];
#pragma unroll
    for (int j = 0; j < 2; j++)
#pragma unroll
        for (int i = 0; i < 4; i++) acc[j][i] = (f32x4){0.f, 0.f, 0.f, 0.f};

#pragma unroll
    for (int st = 0; st < 2; st++) {
        const int sb = p * 64 + st * 32 + quad * 8;
        bf16x8 af[2], bfv[4];
#pragma unroll
        for (int j = 0; j < 2; j++)
            af[j] = *(const bf16x8*)&sap[(size_t)((kth * 2 + j) * 16 + lm) * SP + sb];
#pragma unroll
        for (int i = 0; i < 4; i++)
            bfv[i] = *(const bf16x8*)&xnp[(size_t)((nh * 4 + i) * 16 + lm) * SP + sb];
#pragma unroll
        for (int j = 0; j < 2; j++)
#pragma unroll
            for (int i = 0; i < 4; i++)
                acc[j][i] = __builtin_amdgcn_mfma_f32_16x16x32_bf16(af[j], bfv[i], acc[j][i], 0, 0, 0);
    }

    float* vp = vladp + ((size_t)n * NSPLIT + p) * KD;
#pragma unroll
    for (int j = 0; j < 2; j++)
#pragma unroll
        for (int i = 0; i < 4; i++) {
            const int kq = (kth * 2 + j) * 4 + quad;          // k = kq*4 + r
            const int d  = (nh * 4 + i) * 16 + lm;
            *(f32x4*)&vp[(size_t)(kq * DD + d) * 4] = acc[j][i];
        }

    if (t < KK) {
        float sm = 0.f;
        const unsigned short* rp = &sap[(size_t)t * SP + p * 64];
#pragma unroll
        for (int c8 = 0; c8 < 8; c8++) {
            const bf16x8 v = *(const bf16x8*)&rp[c8 * 8];
#pragma unroll
            for (int j = 0; j < 8; j++) sm += bf2f((unsigned short)v[j]);
        }
        sasump[((size_t)n * NSPLIT + p) * KK + t] = sm;
    }
}

// ---------------------------------------------------------------------------
// K4: reduce NSPLIT partials (f32x4 vector reads), subtract centroids*sasum,
// L2-norm over k, write vladn.  grid (DD/16=8, N) = 256 blocks.
// thread: kq = t&15 (k=kq*4+r), d = dg*16 + (t>>4).
// ---------------------------------------------------------------------------
__global__ __launch_bounds__(256)
void vlad_finish(const float* __restrict__ vladp, const float* __restrict__ sasump,
                 const float* __restrict__ centroids, float* __restrict__ vladn)
{
    const int dg = blockIdx.x;
    const int n  = blockIdx.y;
    const int t  = threadIdx.x;
    const int kq = t & 15;
    const int d  = dg * 16 + (t >> 4);

    __shared__ float sas[KK];
    if (t < KK) {
        float sm = 0.f;
#pragma unroll
        for (int p = 0; p < NSPLIT; p++) sm += sasump[((size_t)n * NSPLIT + p) * KK + t];
        sas[t] = sm;
    }
    __syncthreads();

    f32x4 v = (f32x4){0.f, 0.f, 0.f, 0.f};
#pragma unroll
    for (int p = 0; p < NSPLIT; p++) {
        const f32x4 pr = *(const f32x4*)&vladp[((size_t)n * NSPLIT + p) * KD + (size_t)(kq * DD + d) * 4];
        v += pr;
    }
#pragma unroll
    for (int r = 0; r < 4; r++)
        v[r] -= centroids[(size_t)(kq * 4 + r) * DD + d] * sas[kq * 4 + r];

    float ssq = v[0] * v[0] + v[1] * v[1] + v[2] * v[2] + v[3] * v[3];
    ssq += __shfl_xor(ssq, 1, 64);
    ssq += __shfl_xor(ssq, 2, 64);
    ssq += __shfl_xor(ssq, 4, 64);
    ssq += __shfl_xor(ssq, 8, 64);               // full 16-kq group for this d
    const float scale = 1.f / fmaxf(sqrtf(ssq), 1e-12f);

    float* vo = vladn + (size_t)n * KD;
#pragma unroll
    for (int r = 0; r < 4; r++)
        vo[(size_t)(kq * 4 + r) * DD + d] = v[r] * scale;
}

// ---------------------------------------------------------------------------
// K5: projection via MFMA, barrier-free, no LDS.
// out[n][o] = vladn[n][c] . Wproj[o][c]; A=vladn (m=n), B=Wproj (ndim=o), k=c.
// grid (OUT/64=16, PSPLIT=32) = 512 blocks; 8 K-steps of 32 c; operands packed
// to bf16 in-register from independent float4 loads.
// ---------------------------------------------------------------------------
__global__ __launch_bounds__(256)
void proj_mfma(const float* __restrict__ vladn, const float* __restrict__ Wproj,
               float* __restrict__ outp)
{
    const int o0 = blockIdx.x * 64;
    const int c0 = blockIdx.y * (KD / PSPLIT);   // 256-wide c slice
    const int t  = threadIdx.x;
    const int l  = t & 63;
    const int w  = t >> 6;
    const int lm = l & 15, quad = l >> 4;
    const int o  = o0 + w * 16 + lm;

    f32x4 acc[2];
    acc[0] = (f32x4){0.f, 0.f, 0.f, 0.f};
    acc[1] = (f32x4){0.f, 0.f, 0.f, 0.f};

#pragma unroll 2
    for (int kt = 0; kt < 8; kt++) {
        const int c = c0 + kt * 32 + quad * 8;
        const float4 b0 = *(const float4*)&Wproj[(size_t)o * KD + c];
        const float4 b1 = *(const float4*)&Wproj[(size_t)o * KD + c + 4];
        float4 a00 = *(const float4*)&vladn[(size_t)(0 * 16 + lm) * KD + c];
        float4 a01 = *(const float4*)&vladn[(size_t)(0 * 16 + lm) * KD + c + 4];
        float4 a10 = *(const float4*)&vladn[(size_t)(16 + lm) * KD + c];
        float4 a11 = *(const float4*)&vladn[(size_t)(16 + lm) * KD + c + 4];
        union { unsigned int u[4]; bf16x8 v; } ub, ua0, ua1;
        ub.u[0] = pk_bf16(b0.x, b0.y); ub.u[1] = pk_bf16(b0.z, b0.w);
        ub.u[2] = pk_bf16(b1.x, b1.y); ub.u[3] = pk_bf16(b1.z, b1.w);
        ua0.u[0] = pk_bf16(a00.x, a00.y); ua0.u[1] = pk_bf16(a00.z, a00.w);
        ua0.u[2] = pk_bf16(a01.x, a01.y); ua0.u[3] = pk_bf16(a01.z, a01.w);
        ua1.u[0] = pk_bf16(a10.x, a10.y); ua1.u[1] = pk_bf16(a10.z, a10.w);
        ua1.u[2] = pk_bf16(a11.x, a11.y); ua1.u[3] = pk_bf16(a11.z, a11.w);
        acc[0] = __builtin_amdgcn_mfma_f32_16x16x32_bf16(ua0.v, ub.v, acc[0], 0, 0, 0);
        acc[1] = __builtin_amdgcn_mfma_f32_16x16x32_bf16(ua1.v, ub.v, acc[1], 0, 0, 0);
    }

    // C layout: col lm -> o (matches B), row quad*4+r -> n = a*16+quad*4+r
#pragma unroll
    for (int a = 0; a < 2; a++)
#pragma unroll
        for (int r = 0; r < 4; r++) {
            const int nn = a * 16 + quad * 4 + r;
            outp[((size_t)blockIdx.y * NB + nn) * OUTD + o] = acc[a][r];
        }
}

// ---------------------------------------------------------------------------
// K6: sum projection partials + bproj, final L2 norm over OUT, write d_out.
// ---------------------------------------------------------------------------
__global__ __launch_bounds__(256)
void final_norm_kernel(const float* __restrict__ outp, const float* __restrict__ bproj,
                       float* __restrict__ out)
{
    const int n = blockIdx.x;
    const int t = threadIdx.x;
    const int o4 = t * 4;

    float4 a = *(const float4*)&bproj[o4];
#pragma unroll
    for (int p = 0; p < PSPLIT; p++) {
        const float4 pr = *(const float4*)&outp[((size_t)p * NB + n) * OUTD + o4];
        a.x += pr.x; a.y += pr.y; a.z += pr.z; a.w += pr.w;
    }
    float ssp = a.x * a.x + a.y * a.y + a.z * a.z + a.w * a.w;
#pragma unroll
    for (int off = 32; off > 0; off >>= 1) ssp += __shfl_down(ssp, off, 64);
    __shared__ float rs[4];
    if ((t & 63) == 0) rs[t >> 6] = ssp;
    __syncthreads();
    const float total = rs[0] + rs[1] + rs[2] + rs[3];
    const float scale = 1.f / fmaxf(sqrtf(total), 1e-12f);
    float4 o;
    o.x = a.x * scale; o.y = a.y * scale; o.z = a.z * scale; o.w = a.w * scale;
    *(float4*)&out[(size_t)n * OUTD + o4] = o;
}

// ---------------------------------------------------------------------------
extern "C" void kernel_launch(void* const* d_in, const int* in_sizes, int n_in,
                              void* d_out, int out_size, void* d_ws, size_t ws_size,
                              hipStream_t stream)
{
    const float* x         = (const float*)d_in[0];
    const float* Wpool     = (const float*)d_in[1];
    const float* bpool     = (const float*)d_in[2];
    const float* Wconv     = (const float*)d_in[3];
    const float* bconv     = (const float*)d_in[4];
    const float* centroids = (const float*)d_in[5];
    const float* Wproj     = (const float*)d_in[6];
    const float* bproj     = (const float*)d_in[7];
    float* out = (float*)d_out;
    char*  wsb = (char*)d_ws;

    unsigned short* xn     = (unsigned short*)(wsb + OFF_XN);
    unsigned short* sa     = (unsigned short*)(wsb + OFF_SA);
    unsigned short* Wpk    = (unsigned short*)(wsb + OFF_WPK);
    unsigned short* Wck    = (unsigned short*)(wsb + OFF_WCK);
    float*          vladp  = (float*)(wsb + OFF_VLADP);
    float*          sasump = (float*)(wsb + OFF_SASUM);
    float*          vladn  = (float*)(wsb + OFF_VLADN);
    float*          outp   = (float*)(wsb + OFF_OUTP);

    pack_weights<<<dim3(9), 256, 0, stream>>>(Wpool, Wconv, Wpk, Wck);
    pool_norm_assign<<<dim3(SP / 16, NB), 256, 0, stream>>>(x, Wpk, bpool, Wck, bconv, xn, sa);
    vlad_mfma<<<dim3(NSPLIT, NB), 256, 0, stream>>>(xn, sa, vladp, sasump);
    vlad_finish<<<dim3(DD / 16, NB), 256, 0, stream>>>(vladp, sasump, centroids, vladn);
    proj_mfma<<<dim3(OUTD / 64, PSPLIT), 256, 0, stream>>>(vladn, Wproj, outp);
    final_norm_kernel<<<dim3(NB), 256, 0, stream>>>(outp, bproj, out);
}